// Round 20
// baseline (5947.506 us; speedup 1.0000x reference)
//
#include <hip/hip_runtime.h>

#define NB 64
#define NT 256
#define ND 1024
#define NH 1024
#define G4 4096

typedef _Float16 half_t;
typedef half_t v8h __attribute__((ext_vector_type(8)));
typedef half_t h4  __attribute__((ext_vector_type(4)));
typedef float  v4f __attribute__((ext_vector_type(4)));

#define XPLANE ((size_t)NB * NT * ND)
#define HPLANE ((size_t)NB * NH)       // halves per (slot, combo) — single plane
#define WREG   16384                   // halves per (combo,jp,gt,kh) region (32 KB)

// ---- one-time: x (f32, B,T,D) -> fp16 single plane, transposed to [t][b][d] ----
__global__ void cvt_x(const float* __restrict__ x, half_t* __restrict__ xh) {
    const int row = blockIdx.x;             // row = b*256 + t
    const int b = row >> 8, t = row & 255;
    const int o = threadIdx.x * 4;
    const float4 v = *(const float4*)(x + (size_t)row * ND + o);
    const size_t d = ((size_t)t * NB + b) * ND + o;
    h4 hh;
    hh.x = (half_t)v.x; hh.y = (half_t)v.y;
    hh.z = (half_t)v.z; hh.w = (half_t)v.w;
    *(h4*)(xh + d) = hh;
}

// ---- one-time weight pack (r14-proven): region (combo,jp,gt,kh): [ki][lane][8] ----
__global__ void transpose_pack(const float* __restrict__ fw_Wx,
                               const float* __restrict__ fw_Wh,
                               const float* __restrict__ bw_Wx,
                               const float* __restrict__ bw_Wh,
                               half_t* __restrict__ WT) {
    const int z = blockIdx.z;
    const int combo = z >> 1;
    const int half  = z & 1;               // 0 -> Wx, 1 -> Wh (== kh)
    const int layer = combo >> 1, dirb = combo & 1;
    const float* src = half ? (dirb ? bw_Wh : fw_Wh) : (dirb ? bw_Wx : fw_Wx);
    src += (size_t)layer * ND * G4;
    const int n0 = blockIdx.x * 64, k0 = blockIdx.y * 64;
    __shared__ float tile[64][65];
    const int t = threadIdx.x;             // 256 threads
    #pragma unroll
    for (int it = 0; it < 4; ++it) {
        const int kr = it * 16 + (t >> 4);
        const int nc = (t & 15) * 4;
        const float4 v = *(const float4*)(src + (size_t)(k0 + kr) * G4 + n0 + nc);
        tile[kr][nc + 0] = v.x; tile[kr][nc + 1] = v.y;
        tile[kr][nc + 2] = v.z; tile[kr][nc + 3] = v.w;
    }
    __syncthreads();
    #pragma unroll
    for (int it = 0; it < 4; ++it) {
        const int nr = it * 16 + (t >> 4);
        const int kc = (t & 15) * 4;
        h4 hv;
        hv.x = (half_t)tile[kc + 0][nr];
        hv.y = (half_t)tile[kc + 1][nr];
        hv.z = (half_t)tile[kc + 2][nr];
        hv.w = (half_t)tile[kc + 3][nr];
        const int n = n0 + nr;                 // 0..4095
        const int kr1 = k0 + kc;               // 0..1023 within this kh
        const int gt = n >> 10, j = n & 1023;
        const int jp = j >> 4, l15j = j & 15;
        const int ki = kr1 >> 5, g2 = (kr1 >> 3) & 3, e0 = kr1 & 7;
        const int lane2 = g2 * 16 + l15j;
        const size_t r = (((size_t)combo * 64 + jp) * 4 + gt) * 2 + half;
        *(h4*)(WT + r * WREG + (size_t)ki * 512 + lane2 * 8 + e0) = hv;
    }
}

// ---- sc1 store (write-through past the non-coherent L2) ----
__device__ __forceinline__ void store_h2(half_t* p, half_t a, half_t b) {
    union { half_t h[2]; unsigned int u; } v;
    v.h[0] = a; v.h[1] = b;
    __hip_atomic_store((unsigned int*)p, v.u,
                       __ATOMIC_RELAXED, __HIP_MEMORY_SCOPE_AGENT);
}

// ---- fast cell nonlinearities (native v_exp + fast div; saturation-safe) ----
__device__ __forceinline__ float fsig(float x) {
    return __fdividef(1.f, 1.f + __expf(-x));
}
__device__ __forceinline__ float ftanh(float x) {
    return 1.f - __fdividef(2.f, 1.f + __expf(2.f * x));
}

// ---- persistent scan: 256 blocks x 512 thr; 8 waves = (gate, khalf)
// 256-wide double-buffered chunks (4/step), XOR-swizzled; gate partials
// reduced via LDS atomicAdd into bias-initialized glds.
// hring: [slot 0..NT][combo][B][H] fp16 — monotonic, write-once addresses
__global__ __launch_bounds__(512, 2) void lstm_persistent(
        const half_t* __restrict__ xh,
        const int* __restrict__ lengths,
        const float* __restrict__ fw_b, const float* __restrict__ bw_b,
        const half_t* __restrict__ WT,
        half_t* __restrict__ hring,
        float* __restrict__ out,
        int* __restrict__ bar) {
    const int bid = blockIdx.x;
    const int c  = (bid & 7) >> 1;                 // combo (XCD-pair-local)
    const int jp = ((bid >> 3) << 1) | (bid & 1);  // 0..63
    const int layer = c >> 1, dir = c & 1;
    const int tid = threadIdx.x;
    const int wv = tid >> 6, lane = tid & 63;
    const int gt = wv & 3, kh = wv >> 2;           // gate, K-half
    const int l15 = lane & 15, g = lane >> 4;
    const int j0 = jp * 16;

    // staging role: 256 threads per kh-half; 4 threads per row (64 halves each)
    const int shf  = tid >> 8;                     // which K-half this thread stages
    const int srow = (tid & 255) >> 2;             // 0..63 (batch row)
    const int sks  = (tid & 3) * 64;               // 64-half segment within 256
    const int sswz = (srow & 7) << 3;              // write-side XOR (8-half units)
    const int rswz = (l15 & 7) << 3;               // read-side XOR

    __shared__ half_t alds[2][2][64][256];         // [buf][kh][row][256]  128 KB
    __shared__ float glds[4][NB][17];              // gate accum (bias-init) 17.4 KB
    __shared__ float c_lds[NB][17];
    __shared__ float h_lds[NB][17];
    __shared__ float bias_lds[4][16];
    __shared__ int   len_lds[NB];

    for (int e = tid; e < NB * 16; e += 512) {
        c_lds[e >> 4][e & 15] = 0.f;
        h_lds[e >> 4][e & 15] = 0.f;
    }
    if (tid < NB) len_lds[tid] = lengths[tid];
    if (tid < 64) {
        const int gg = tid >> 4, jj = tid & 15;
        const float* bs = dir ? bw_b : fw_b;
        bias_lds[gg][jj] = bs[(size_t)layer * G4 + gg * NH + j0 + jj];
    }

    // ---- weight preload, pinned ONCE into AGPRs (r14-proven construct) ----
    v8h w[32];
    {
        const half_t* wp = WT + ((((size_t)c * 64 + jp) * 4 + gt) * 2 + kh) * WREG
                         + (size_t)lane * 8;
        #pragma unroll
        for (int ki = 0; ki < 32; ++ki) w[ki] = *(const v8h*)(wp + (size_t)ki * 512);
    }
    #pragma unroll
    for (int ki = 0; ki < 32; ++ki) asm volatile("" : "+a"(w[ki]));
    __syncthreads();

    // ---- per-direction barrier state (128 blocks = 8 groups of 16), r17 ----
    const int id128 = layer * 64 + jp;
    int* gcnt = bar + ((size_t)dir * 8 + (id128 >> 4)) * 16;
    int* root = bar + 256 + dir * 16;
    int* rel  = bar + 320 + dir * 16;

    for (int s = 0; s <= NT; ++s) {
        const bool active = (layer == 0) ? (s < NT) : (s >= 1);
        const int u = (layer == 0) ? s : (s - 1);

        // per-thread staging source (uniform per shf-group), row stride 1024
        const half_t* bsrc = nullptr;
        if (active) {
            if (shf == 0) {
                if (layer == 0) {
                    const int t = dir ? (NT - 1 - u) : u;
                    bsrc = xh + (size_t)t * NB * ND;
                } else {
                    bsrc = hring + ((size_t)s * 4 + dir) * HPLANE;
                }
            } else {
                bsrc = hring + ((size_t)u * 4 + c) * HPLANE;
            }
        }

        // init gate accumulators with bias (ordered before atomicAdds by chunk syncs)
        if (active) {
            for (int e = tid; e < 4 * NB * 16; e += 512) {
                const int gg = e >> 10, rem = e & 1023;
                glds[gg][rem >> 4][rem & 15] = bias_lds[gg][rem & 15];
            }
        }

        v4f acc[4];
        #pragma unroll
        for (int m = 0; m < 4; ++m) acc[m] = (v4f){0.f, 0.f, 0.f, 0.f};

        v8h sh[8];                         // staged regs: 64 halves (one chunk seg)
        if (active) {
            const size_t o0 = (size_t)srow * 1024 + sks;       // chunk 0
            #pragma unroll
            for (int i = 0; i < 8; ++i) sh[i] = *(const v8h*)(bsrc + o0 + i * 8);
        }

        #pragma unroll
        for (int ci = 0; ci < 4; ++ci) {
            if (active) {
                #pragma unroll
                for (int i = 0; i < 8; ++i)
                    *(v8h*)&alds[ci & 1][shf][srow][(sks + i * 8) ^ sswz] = sh[i];
                if (ci < 3) {              // issue prefetch before the barrier
                    const size_t o = (size_t)srow * 1024 + (ci + 1) * 256 + sks;
                    #pragma unroll
                    for (int i = 0; i < 8; ++i) sh[i] = *(const v8h*)(bsrc + o + i * 8);
                }
            }
            __syncthreads();               // chunk ci visible; prior reads drained
            if (active) {
                #pragma unroll
                for (int ki = 0; ki < 8; ++ki) {
                    #pragma unroll
                    for (int m = 0; m < 4; ++m) {
                        v8h ah = *(const v8h*)&alds[ci & 1][kh][m * 16 + l15]
                                              [(ki * 32 + g * 8) ^ rswz];
                        acc[m] = __builtin_amdgcn_mfma_f32_16x16x32_f16(
                                     ah, w[ci * 8 + ki], acc[m], 0, 0, 0);
                    }
                }
            }
        }

        if (active) {
            // reduce kh partials: C/D col = l15 (jj), row = m*16 + g*4 + r (batch)
            #pragma unroll
            for (int m = 0; m < 4; ++m)
                #pragma unroll
                for (int r = 0; r < 4; ++r)
                    atomicAdd(&glds[gt][m * 16 + g * 4 + r][l15], acc[m][r]);
        }
        __syncthreads();

        if (active) {
            const int b = tid >> 3, jj0 = (tid & 7) * 2;
            float hpair[2];
            #pragma unroll
            for (int k2 = 0; k2 < 2; ++k2) {
                const int jj = jj0 + k2;
                const float iv = glds[0][b][jj];
                const float fv = glds[1][b][jj];
                const float gv = glds[2][b][jj];
                const float ov = glds[3][b][jj];
                const float cold = c_lds[b][jj];
                const float hold = h_lds[b][jj];
                const float si = fsig(iv);
                const float sf = fsig(fv);
                const float so = fsig(ov);
                const float cn = sf * cold + si * ftanh(gv);
                const float hn = so * ftanh(cn);
                const bool valid = len_lds[b] > u;   // un-reversed mask (reference quirk)
                const float c2 = valid ? cn : cold;
                const float h2 = valid ? hn : hold;
                c_lds[b][jj] = c2;
                h_lds[b][jj] = h2;
                hpair[k2] = h2;
                if (layer == 1) {
                    const int tout = dir ? (NT - 1 - u) : u;
                    __builtin_nontemporal_store(
                        h2, &out[((size_t)b * NT + tout) * (2 * NH) + dir * NH + j0 + jj]);
                    if (u == NT - 1)
                        __builtin_nontemporal_store(
                            h2, &out[(size_t)NB * NT * (2 * NH) + (size_t)b * (2 * NH)
                                     + dir * NH + j0 + jj]);
                }
            }
            // h handoff into fresh ring slot u+1 (single fp16 plane, sc1 store)
            half_t* hb2 = hring + ((size_t)(u + 1) * 4 + c) * HPLANE
                        + (size_t)b * NH + j0 + jj0;
            store_h2(hb2, (half_t)hpair[0], (half_t)hpair[1]);
        }

        // ---- per-direction barrier: relaxed atomics, no fences (r17-proven) ----
        const int phase = s + 1;
        __syncthreads();                    // vmcnt(0): sc1 h-stores visible
        if (tid == 0) {
            const int a = __hip_atomic_fetch_add(gcnt, 1, __ATOMIC_RELAXED,
                                                 __HIP_MEMORY_SCOPE_AGENT) + 1;
            if (a == phase * 16) {
                const int rr = __hip_atomic_fetch_add(root, 1, __ATOMIC_RELAXED,
                                                      __HIP_MEMORY_SCOPE_AGENT) + 1;
                if (rr == phase * 8)
                    __hip_atomic_store(rel, phase, __ATOMIC_RELAXED,
                                       __HIP_MEMORY_SCOPE_AGENT);
            }
            while (__hip_atomic_load(rel, __ATOMIC_RELAXED,
                                     __HIP_MEMORY_SCOPE_AGENT) < phase)
                __builtin_amdgcn_s_sleep(1);
        }
        __syncthreads();
    }
}

extern "C" void kernel_launch(void* const* d_in, const int* in_sizes, int n_in,
                              void* d_out, int out_size, void* d_ws, size_t ws_size,
                              hipStream_t stream) {
    (void)in_sizes; (void)n_in; (void)out_size; (void)ws_size;
    const float* x     = (const float*)d_in[0];
    const int*   len   = (const int*)d_in[1];
    const float* fw_Wx = (const float*)d_in[2];
    const float* fw_Wh = (const float*)d_in[3];
    const float* fw_b  = (const float*)d_in[4];
    const float* bw_Wx = (const float*)d_in[5];
    const float* bw_Wh = (const float*)d_in[6];
    const float* bw_b  = (const float*)d_in[7];
    float* out = (float*)d_out;

    char* ws = (char*)d_ws;
    size_t off = 0;
    half_t* WT = (half_t*)(ws + off); off += (size_t)2048 * WREG * 2;   // 64 MB
    half_t* xh = (half_t*)(ws + off); off += XPLANE * 2;                // 32 MB
    int* bar = (int*)(ws + off); off += 4096;                           // 4 KB
    half_t* hring = (half_t*)(ws + off);                                // 134.7 MB

    // zero barrier counters + ring slot 0 (4 combos x 128 KB = 512 KB)
    hipMemsetAsync(bar, 0, 4096 + (size_t)4 * HPLANE * 2, stream);

    cvt_x<<<NB * NT, 256, 0, stream>>>(x, xh);

    dim3 tg(G4 / 64, ND / 64, 8);
    transpose_pack<<<tg, 256, 0, stream>>>(fw_Wx, fw_Wh, bw_Wx, bw_Wh, WT);

    void* args[] = {(void*)&xh, (void*)&len, (void*)&fw_b, (void*)&bw_b,
                    (void*)&WT, (void*)&hring, (void*)&out, (void*)&bar};
    hipLaunchCooperativeKernel((void*)lstm_persistent, dim3(256), dim3(512),
                               args, 0, stream);
}

// Round 21
// 2405.840 us; speedup vs baseline: 2.4721x; 2.4721x over previous
//
#include <hip/hip_runtime.h>

#define NB 64
#define NT 256
#define ND 1024
#define NH 1024
#define G4 4096

typedef _Float16 half_t;
typedef half_t v8h __attribute__((ext_vector_type(8)));
typedef half_t h4  __attribute__((ext_vector_type(4)));
typedef float  v4f __attribute__((ext_vector_type(4)));

#define XPLANE ((size_t)NB * NT * ND)
#define HPLANE ((size_t)NB * NH)       // halves per (slot, combo) — single plane
#define WREG   16384                   // halves per (combo,jp,gt,kh) region (32 KB)

// ---- one-time: x (f32, B,T,D) -> fp16 single plane, transposed to [t][b][d] ----
__global__ void cvt_x(const float* __restrict__ x, half_t* __restrict__ xh) {
    const int row = blockIdx.x;             // row = b*256 + t
    const int b = row >> 8, t = row & 255;
    const int o = threadIdx.x * 4;
    const float4 v = *(const float4*)(x + (size_t)row * ND + o);
    const size_t d = ((size_t)t * NB + b) * ND + o;
    h4 hh;
    hh.x = (half_t)v.x; hh.y = (half_t)v.y;
    hh.z = (half_t)v.z; hh.w = (half_t)v.w;
    *(h4*)(xh + d) = hh;
}

// ---- one-time weight pack (r14-proven): region (combo,jp,gt,kh): [ki][lane][8] ----
__global__ void transpose_pack(const float* __restrict__ fw_Wx,
                               const float* __restrict__ fw_Wh,
                               const float* __restrict__ bw_Wx,
                               const float* __restrict__ bw_Wh,
                               half_t* __restrict__ WT) {
    const int z = blockIdx.z;
    const int combo = z >> 1;
    const int half  = z & 1;               // 0 -> Wx, 1 -> Wh (== kh)
    const int layer = combo >> 1, dirb = combo & 1;
    const float* src = half ? (dirb ? bw_Wh : fw_Wh) : (dirb ? bw_Wx : fw_Wx);
    src += (size_t)layer * ND * G4;
    const int n0 = blockIdx.x * 64, k0 = blockIdx.y * 64;
    __shared__ float tile[64][65];
    const int t = threadIdx.x;             // 256 threads
    #pragma unroll
    for (int it = 0; it < 4; ++it) {
        const int kr = it * 16 + (t >> 4);
        const int nc = (t & 15) * 4;
        const float4 v = *(const float4*)(src + (size_t)(k0 + kr) * G4 + n0 + nc);
        tile[kr][nc + 0] = v.x; tile[kr][nc + 1] = v.y;
        tile[kr][nc + 2] = v.z; tile[kr][nc + 3] = v.w;
    }
    __syncthreads();
    #pragma unroll
    for (int it = 0; it < 4; ++it) {
        const int nr = it * 16 + (t >> 4);
        const int kc = (t & 15) * 4;
        h4 hv;
        hv.x = (half_t)tile[kc + 0][nr];
        hv.y = (half_t)tile[kc + 1][nr];
        hv.z = (half_t)tile[kc + 2][nr];
        hv.w = (half_t)tile[kc + 3][nr];
        const int n = n0 + nr;                 // 0..4095
        const int kr1 = k0 + kc;               // 0..1023 within this kh
        const int gt = n >> 10, j = n & 1023;
        const int jp = j >> 4, l15j = j & 15;
        const int ki = kr1 >> 5, g2 = (kr1 >> 3) & 3, e0 = kr1 & 7;
        const int lane2 = g2 * 16 + l15j;
        const size_t r = (((size_t)combo * 64 + jp) * 4 + gt) * 2 + half;
        *(h4*)(WT + r * WREG + (size_t)ki * 512 + lane2 * 8 + e0) = hv;
    }
}

// ---- sc1 store (write-through past the non-coherent L2) ----
__device__ __forceinline__ void store_h2(half_t* p, half_t a, half_t b) {
    union { half_t h[2]; unsigned int u; } v;
    v.h[0] = a; v.h[1] = b;
    __hip_atomic_store((unsigned int*)p, v.u,
                       __ATOMIC_RELAXED, __HIP_MEMORY_SCOPE_AGENT);
}

// ---- fast cell nonlinearities (native v_exp + fast div; saturation-safe) ----
__device__ __forceinline__ float fsig(float x) {
    return __fdividef(1.f, 1.f + __expf(-x));
}
__device__ __forceinline__ float ftanh(float x) {
    return 1.f - __fdividef(2.f, 1.f + __expf(2.f * x));
}

// ---- persistent scan: 256 blocks x 512 thr; 8 waves = (gate, khalf)
// A single fp16 plane, double-buffered LDS chunks (XOR-swizzled), 1 barrier/chunk.
// hring: [slot 0..NT][combo][B][H] fp16 — monotonic, write-once addresses
__global__ __launch_bounds__(512, 2) void lstm_persistent(
        const half_t* __restrict__ xh,
        const int* __restrict__ lengths,
        const float* __restrict__ fw_b, const float* __restrict__ bw_b,
        const half_t* __restrict__ WT,
        half_t* __restrict__ hring,
        float* __restrict__ out,
        int* __restrict__ bar) {
    const int bid = blockIdx.x;
    const int c  = (bid & 7) >> 1;                 // combo (XCD-pair-local)
    const int jp = ((bid >> 3) << 1) | (bid & 1);  // 0..63
    const int layer = c >> 1, dir = c & 1;
    const int tid = threadIdx.x;
    const int wv = tid >> 6, lane = tid & 63;
    const int gt = wv & 3, kh = wv >> 2;           // gate, K-half
    const int l15 = lane & 15, g = lane >> 4;
    const int j0 = jp * 16;

    // staging role: 256 threads per kh-half; 4 threads per row (32 halves each)
    const int shf  = tid >> 8;                     // which K-half this thread stages
    const int srow = (tid & 255) >> 2;             // 0..63 (batch row)
    const int sks  = (tid & 3) * 32;               // 32-half segment within 128
    const int sswz = (srow & 7) << 3;              // write-side XOR (8-half units)
    const int rswz = (l15 & 7) << 3;               // read-side XOR

    __shared__ half_t alds[2][2][64][128];         // [buf][kh][row][128]  64 KB
    __shared__ float glds[4][2][NB][17];           // 34.8 KB
    __shared__ float c_lds[NB][17];
    __shared__ float h_lds[NB][17];
    __shared__ float bias_lds[4][16];
    __shared__ int   len_lds[NB];

    for (int e = tid; e < NB * 16; e += 512) {
        c_lds[e >> 4][e & 15] = 0.f;
        h_lds[e >> 4][e & 15] = 0.f;
    }
    if (tid < NB) len_lds[tid] = lengths[tid];
    if (tid < 64) {
        const int gg = tid >> 4, jj = tid & 15;
        const float* bs = dir ? bw_b : fw_b;
        bias_lds[gg][jj] = bs[(size_t)layer * G4 + gg * NH + j0 + jj];
    }

    // ---- weight preload, pinned ONCE into AGPRs (r14-proven construct) ----
    v8h w[32];
    {
        const half_t* wp = WT + ((((size_t)c * 64 + jp) * 4 + gt) * 2 + kh) * WREG
                         + (size_t)lane * 8;
        #pragma unroll
        for (int ki = 0; ki < 32; ++ki) w[ki] = *(const v8h*)(wp + (size_t)ki * 512);
    }
    #pragma unroll
    for (int ki = 0; ki < 32; ++ki) asm volatile("" : "+a"(w[ki]));
    __syncthreads();

    // ---- per-direction barrier state (128 blocks = 8 groups of 16), r17 ----
    const int id128 = layer * 64 + jp;
    int* gcnt = bar + ((size_t)dir * 8 + (id128 >> 4)) * 16;
    int* root = bar + 256 + dir * 16;
    int* rel  = bar + 320 + dir * 16;

    for (int s = 0; s <= NT; ++s) {
        const bool active = (layer == 0) ? (s < NT) : (s >= 1);
        const int u = (layer == 0) ? s : (s - 1);

        // per-thread staging source (uniform per shf-group), row stride 1024
        const half_t* bsrc = nullptr;
        if (active) {
            if (shf == 0) {
                if (layer == 0) {
                    const int t = dir ? (NT - 1 - u) : u;
                    bsrc = xh + (size_t)t * NB * ND;
                } else {
                    bsrc = hring + ((size_t)s * 4 + dir) * HPLANE;
                }
            } else {
                bsrc = hring + ((size_t)u * 4 + c) * HPLANE;
            }
        }

        v4f acc[4];
        #pragma unroll
        for (int m = 0; m < 4; ++m) acc[m] = (v4f){0.f, 0.f, 0.f, 0.f};

        v8h sh[4];                         // staged regs: 32 halves (one chunk seg)
        if (active) {
            const size_t o0 = (size_t)srow * 1024 + sks;       // chunk 0
            #pragma unroll
            for (int i = 0; i < 4; ++i) sh[i] = *(const v8h*)(bsrc + o0 + i * 8);
        }

        #pragma unroll
        for (int ci = 0; ci < 8; ++ci) {
            if (active) {
                #pragma unroll
                for (int i = 0; i < 4; ++i)
                    *(v8h*)&alds[ci & 1][shf][srow][(sks + i * 8) ^ sswz] = sh[i];
                if (ci < 7) {              // issue prefetch before the barrier
                    const size_t o = (size_t)srow * 1024 + (ci + 1) * 128 + sks;
                    #pragma unroll
                    for (int i = 0; i < 4; ++i) sh[i] = *(const v8h*)(bsrc + o + i * 8);
                }
            }
            __syncthreads();               // chunk ci visible; prior reads drained
            if (active) {
                #pragma unroll
                for (int ki = 0; ki < 4; ++ki) {
                    #pragma unroll
                    for (int m = 0; m < 4; ++m) {
                        v8h ah = *(const v8h*)&alds[ci & 1][kh][m * 16 + l15]
                                              [(ki * 32 + g * 8) ^ rswz];
                        acc[m] = __builtin_amdgcn_mfma_f32_16x16x32_f16(
                                     ah, w[ci * 4 + ki], acc[m], 0, 0, 0);
                    }
                }
            }
        }

        if (active) {
            // C/D: col = l15 (jj), row-in-Mtile = g*4 + r (batch)
            #pragma unroll
            for (int m = 0; m < 4; ++m)
                #pragma unroll
                for (int r = 0; r < 4; ++r)
                    glds[gt][kh][m * 16 + g * 4 + r][l15] = acc[m][r];
        }
        __syncthreads();

        if (active) {
            const int b = tid >> 3, jj0 = (tid & 7) * 2;
            float hpair[2];
            #pragma unroll
            for (int k2 = 0; k2 < 2; ++k2) {
                const int jj = jj0 + k2;
                const float iv = glds[0][0][b][jj] + glds[0][1][b][jj] + bias_lds[0][jj];
                const float fv = glds[1][0][b][jj] + glds[1][1][b][jj] + bias_lds[1][jj];
                const float gv = glds[2][0][b][jj] + glds[2][1][b][jj] + bias_lds[2][jj];
                const float ov = glds[3][0][b][jj] + glds[3][1][b][jj] + bias_lds[3][jj];
                const float cold = c_lds[b][jj];
                const float hold = h_lds[b][jj];
                const float si = fsig(iv);
                const float sf = fsig(fv);
                const float so = fsig(ov);
                const float cn = sf * cold + si * ftanh(gv);
                const float hn = so * ftanh(cn);
                const bool valid = len_lds[b] > u;   // un-reversed mask (reference quirk)
                const float c2 = valid ? cn : cold;
                const float h2 = valid ? hn : hold;
                c_lds[b][jj] = c2;
                h_lds[b][jj] = h2;
                hpair[k2] = h2;
                if (layer == 1) {
                    const int tout = dir ? (NT - 1 - u) : u;
                    __builtin_nontemporal_store(
                        h2, &out[((size_t)b * NT + tout) * (2 * NH) + dir * NH + j0 + jj]);
                    if (u == NT - 1)
                        __builtin_nontemporal_store(
                            h2, &out[(size_t)NB * NT * (2 * NH) + (size_t)b * (2 * NH)
                                     + dir * NH + j0 + jj]);
                }
            }
            // h handoff into fresh ring slot u+1 (single fp16 plane, sc1 store)
            half_t* hb2 = hring + ((size_t)(u + 1) * 4 + c) * HPLANE
                        + (size_t)b * NH + j0 + jj0;
            store_h2(hb2, (half_t)hpair[0], (half_t)hpair[1]);
        }

        // ---- per-direction barrier: relaxed atomics, no fences (r17-proven) ----
        const int phase = s + 1;
        __syncthreads();                    // vmcnt(0): sc1 h-stores visible
        if (tid == 0) {
            const int a = __hip_atomic_fetch_add(gcnt, 1, __ATOMIC_RELAXED,
                                                 __HIP_MEMORY_SCOPE_AGENT) + 1;
            if (a == phase * 16) {
                const int rr = __hip_atomic_fetch_add(root, 1, __ATOMIC_RELAXED,
                                                      __HIP_MEMORY_SCOPE_AGENT) + 1;
                if (rr == phase * 8)
                    __hip_atomic_store(rel, phase, __ATOMIC_RELAXED,
                                       __HIP_MEMORY_SCOPE_AGENT);
            }
            while (__hip_atomic_load(rel, __ATOMIC_RELAXED,
                                     __HIP_MEMORY_SCOPE_AGENT) < phase)
                __builtin_amdgcn_s_sleep(1);
        }
        __syncthreads();
    }
}

extern "C" void kernel_launch(void* const* d_in, const int* in_sizes, int n_in,
                              void* d_out, int out_size, void* d_ws, size_t ws_size,
                              hipStream_t stream) {
    (void)in_sizes; (void)n_in; (void)out_size; (void)ws_size;
    const float* x     = (const float*)d_in[0];
    const int*   len   = (const int*)d_in[1];
    const float* fw_Wx = (const float*)d_in[2];
    const float* fw_Wh = (const float*)d_in[3];
    const float* fw_b  = (const float*)d_in[4];
    const float* bw_Wx = (const float*)d_in[5];
    const float* bw_Wh = (const float*)d_in[6];
    const float* bw_b  = (const float*)d_in[7];
    float* out = (float*)d_out;

    char* ws = (char*)d_ws;
    size_t off = 0;
    half_t* WT = (half_t*)(ws + off); off += (size_t)2048 * WREG * 2;   // 64 MB
    half_t* xh = (half_t*)(ws + off); off += XPLANE * 2;                // 32 MB
    int* bar = (int*)(ws + off); off += 4096;                           // 4 KB
    half_t* hring = (half_t*)(ws + off);                                // 134.7 MB

    // zero barrier counters + ring slot 0 (4 combos x 128 KB = 512 KB)
    hipMemsetAsync(bar, 0, 4096 + (size_t)4 * HPLANE * 2, stream);

    cvt_x<<<NB * NT, 256, 0, stream>>>(x, xh);

    dim3 tg(G4 / 64, ND / 64, 8);
    transpose_pack<<<tg, 256, 0, stream>>>(fw_Wx, fw_Wh, bw_Wx, bw_Wh, WT);

    void* args[] = {(void*)&xh, (void*)&len, (void*)&fw_b, (void*)&bw_b,
                    (void*)&WT, (void*)&hring, (void*)&out, (void*)&bar};
    hipLaunchCooperativeKernel((void*)lstm_persistent, dim3(256), dim3(512),
                               args, 0, stream);
}

// Round 22
// 2357.027 us; speedup vs baseline: 2.5233x; 1.0207x over previous
//
#include <hip/hip_runtime.h>

#define NB 64
#define NT 256
#define ND 1024
#define NH 1024
#define G4 4096

typedef _Float16 half_t;
typedef half_t v8h __attribute__((ext_vector_type(8)));
typedef half_t h4  __attribute__((ext_vector_type(4)));
typedef float  v4f __attribute__((ext_vector_type(4)));

#define XPLANE ((size_t)NB * NT * ND)
#define HPLANE ((size_t)NB * NH)       // halves per (slot, combo) — single plane
#define WREG   16384                   // halves per (combo,jp,gt,kh) region (32 KB)

// ---- one-time: x (f32, B,T,D) -> fp16 single plane, transposed to [t][b][d] ----
__global__ void cvt_x(const float* __restrict__ x, half_t* __restrict__ xh) {
    const int row = blockIdx.x;             // row = b*256 + t
    const int b = row >> 8, t = row & 255;
    const int o = threadIdx.x * 4;
    const float4 v = *(const float4*)(x + (size_t)row * ND + o);
    const size_t d = ((size_t)t * NB + b) * ND + o;
    h4 hh;
    hh.x = (half_t)v.x; hh.y = (half_t)v.y;
    hh.z = (half_t)v.z; hh.w = (half_t)v.w;
    *(h4*)(xh + d) = hh;
}

// ---- one-time weight pack (r14-proven): region (combo,jp,gt,kh): [ki][lane][8] ----
__global__ void transpose_pack(const float* __restrict__ fw_Wx,
                               const float* __restrict__ fw_Wh,
                               const float* __restrict__ bw_Wx,
                               const float* __restrict__ bw_Wh,
                               half_t* __restrict__ WT) {
    const int z = blockIdx.z;
    const int combo = z >> 1;
    const int half  = z & 1;               // 0 -> Wx, 1 -> Wh (== kh)
    const int layer = combo >> 1, dirb = combo & 1;
    const float* src = half ? (dirb ? bw_Wh : fw_Wh) : (dirb ? bw_Wx : fw_Wx);
    src += (size_t)layer * ND * G4;
    const int n0 = blockIdx.x * 64, k0 = blockIdx.y * 64;
    __shared__ float tile[64][65];
    const int t = threadIdx.x;             // 256 threads
    #pragma unroll
    for (int it = 0; it < 4; ++it) {
        const int kr = it * 16 + (t >> 4);
        const int nc = (t & 15) * 4;
        const float4 v = *(const float4*)(src + (size_t)(k0 + kr) * G4 + n0 + nc);
        tile[kr][nc + 0] = v.x; tile[kr][nc + 1] = v.y;
        tile[kr][nc + 2] = v.z; tile[kr][nc + 3] = v.w;
    }
    __syncthreads();
    #pragma unroll
    for (int it = 0; it < 4; ++it) {
        const int nr = it * 16 + (t >> 4);
        const int kc = (t & 15) * 4;
        h4 hv;
        hv.x = (half_t)tile[kc + 0][nr];
        hv.y = (half_t)tile[kc + 1][nr];
        hv.z = (half_t)tile[kc + 2][nr];
        hv.w = (half_t)tile[kc + 3][nr];
        const int n = n0 + nr;                 // 0..4095
        const int kr1 = k0 + kc;               // 0..1023 within this kh
        const int gt = n >> 10, j = n & 1023;
        const int jp = j >> 4, l15j = j & 15;
        const int ki = kr1 >> 5, g2 = (kr1 >> 3) & 3, e0 = kr1 & 7;
        const int lane2 = g2 * 16 + l15j;
        const size_t r = (((size_t)combo * 64 + jp) * 4 + gt) * 2 + half;
        *(h4*)(WT + r * WREG + (size_t)ki * 512 + lane2 * 8 + e0) = hv;
    }
}

// ---- sc1 store (write-through past the non-coherent L2) ----
__device__ __forceinline__ void store_h2(half_t* p, half_t a, half_t b) {
    union { half_t h[2]; unsigned int u; } v;
    v.h[0] = a; v.h[1] = b;
    __hip_atomic_store((unsigned int*)p, v.u,
                       __ATOMIC_RELAXED, __HIP_MEMORY_SCOPE_AGENT);
}

// ---- fast cell nonlinearities (native v_exp + fast div; saturation-safe) ----
__device__ __forceinline__ float fsig(float x) {
    return __fdividef(1.f, 1.f + __expf(-x));
}
__device__ __forceinline__ float ftanh(float x) {
    return 1.f - __fdividef(2.f, 1.f + __expf(2.f * x));
}

// ---- persistent scan: 256 blocks x 512 thr; 8 waves = (gate, khalf)
// A single fp16 plane, double-buffered LDS chunks (XOR-swizzled), 1 barrier/chunk.
// FLAT per-combo barrier: one atomicAdd + direct counter poll (no root/rel hops).
// hring: [slot 0..NT][combo][B][H] fp16 — monotonic, write-once addresses
__global__ __launch_bounds__(512, 2) void lstm_persistent(
        const half_t* __restrict__ xh,
        const int* __restrict__ lengths,
        const float* __restrict__ fw_b, const float* __restrict__ bw_b,
        const half_t* __restrict__ WT,
        half_t* __restrict__ hring,
        float* __restrict__ out,
        int* __restrict__ bar) {
    const int bid = blockIdx.x;
    const int c  = (bid & 7) >> 1;                 // combo (XCD-pair-local)
    const int jp = ((bid >> 3) << 1) | (bid & 1);  // 0..63
    const int layer = c >> 1, dir = c & 1;
    const int tid = threadIdx.x;
    const int wv = tid >> 6, lane = tid & 63;
    const int gt = wv & 3, kh = wv >> 2;           // gate, K-half
    const int l15 = lane & 15, g = lane >> 4;
    const int j0 = jp * 16;

    // staging role: 256 threads per kh-half; 4 threads per row (32 halves each)
    const int shf  = tid >> 8;                     // which K-half this thread stages
    const int srow = (tid & 255) >> 2;             // 0..63 (batch row)
    const int sks  = (tid & 3) * 32;               // 32-half segment within 128
    const int sswz = (srow & 7) << 3;              // write-side XOR (8-half units)
    const int rswz = (l15 & 7) << 3;               // read-side XOR

    __shared__ half_t alds[2][2][64][128];         // [buf][kh][row][128]  64 KB
    __shared__ float glds[4][2][NB][17];           // 34.8 KB
    __shared__ float c_lds[NB][17];
    __shared__ float h_lds[NB][17];
    __shared__ float bias_lds[4][16];
    __shared__ int   len_lds[NB];

    for (int e = tid; e < NB * 16; e += 512) {
        c_lds[e >> 4][e & 15] = 0.f;
        h_lds[e >> 4][e & 15] = 0.f;
    }
    if (tid < NB) len_lds[tid] = lengths[tid];
    if (tid < 64) {
        const int gg = tid >> 4, jj = tid & 15;
        const float* bs = dir ? bw_b : fw_b;
        bias_lds[gg][jj] = bs[(size_t)layer * G4 + gg * NH + j0 + jj];
    }

    // ---- weight preload, pinned ONCE into AGPRs (r14-proven construct) ----
    v8h w[32];
    {
        const half_t* wp = WT + ((((size_t)c * 64 + jp) * 4 + gt) * 2 + kh) * WREG
                         + (size_t)lane * 8;
        #pragma unroll
        for (int ki = 0; ki < 32; ++ki) w[ki] = *(const v8h*)(wp + (size_t)ki * 512);
    }
    #pragma unroll
    for (int ki = 0; ki < 32; ++ki) asm volatile("" : "+a"(w[ki]));
    __syncthreads();

    // ---- flat per-combo barrier counters (cache-line separated, monotonic) ----
    int* cnt_own = bar + c * 32;
    int* cnt_dep = bar + (c & 1) * 32;             // same-direction L0 (L1 only)

    for (int s = 0; s <= NT; ++s) {
        const bool active = (layer == 0) ? (s < NT) : (s >= 1);
        const int u = (layer == 0) ? s : (s - 1);

        // per-thread staging source (uniform per shf-group), row stride 1024
        const half_t* bsrc = nullptr;
        if (active) {
            if (shf == 0) {
                if (layer == 0) {
                    const int t = dir ? (NT - 1 - u) : u;
                    bsrc = xh + (size_t)t * NB * ND;
                } else {
                    bsrc = hring + ((size_t)s * 4 + dir) * HPLANE;
                }
            } else {
                bsrc = hring + ((size_t)u * 4 + c) * HPLANE;
            }
        }

        v4f acc[4];
        #pragma unroll
        for (int m = 0; m < 4; ++m) acc[m] = (v4f){0.f, 0.f, 0.f, 0.f};

        v8h sh[4];                         // staged regs: 32 halves (one chunk seg)
        if (active) {
            const size_t o0 = (size_t)srow * 1024 + sks;       // chunk 0
            #pragma unroll
            for (int i = 0; i < 4; ++i) sh[i] = *(const v8h*)(bsrc + o0 + i * 8);
        }

        #pragma unroll
        for (int ci = 0; ci < 8; ++ci) {
            if (active) {
                #pragma unroll
                for (int i = 0; i < 4; ++i)
                    *(v8h*)&alds[ci & 1][shf][srow][(sks + i * 8) ^ sswz] = sh[i];
                if (ci < 7) {              // issue prefetch before the barrier
                    const size_t o = (size_t)srow * 1024 + (ci + 1) * 128 + sks;
                    #pragma unroll
                    for (int i = 0; i < 4; ++i) sh[i] = *(const v8h*)(bsrc + o + i * 8);
                }
            }
            __syncthreads();               // chunk ci visible; prior reads drained
            if (active) {
                #pragma unroll
                for (int ki = 0; ki < 4; ++ki) {
                    #pragma unroll
                    for (int m = 0; m < 4; ++m) {
                        v8h ah = *(const v8h*)&alds[ci & 1][kh][m * 16 + l15]
                                              [(ki * 32 + g * 8) ^ rswz];
                        acc[m] = __builtin_amdgcn_mfma_f32_16x16x32_f16(
                                     ah, w[ci * 4 + ki], acc[m], 0, 0, 0);
                    }
                }
            }
        }

        if (active) {
            // C/D: col = l15 (jj), row-in-Mtile = g*4 + r (batch)
            #pragma unroll
            for (int m = 0; m < 4; ++m)
                #pragma unroll
                for (int r = 0; r < 4; ++r)
                    glds[gt][kh][m * 16 + g * 4 + r][l15] = acc[m][r];
        }
        __syncthreads();

        if (active) {
            const int b = tid >> 3, jj0 = (tid & 7) * 2;
            float hpair[2];
            #pragma unroll
            for (int k2 = 0; k2 < 2; ++k2) {
                const int jj = jj0 + k2;
                const float iv = glds[0][0][b][jj] + glds[0][1][b][jj] + bias_lds[0][jj];
                const float fv = glds[1][0][b][jj] + glds[1][1][b][jj] + bias_lds[1][jj];
                const float gv = glds[2][0][b][jj] + glds[2][1][b][jj] + bias_lds[2][jj];
                const float ov = glds[3][0][b][jj] + glds[3][1][b][jj] + bias_lds[3][jj];
                const float cold = c_lds[b][jj];
                const float hold = h_lds[b][jj];
                const float si = fsig(iv);
                const float sf = fsig(fv);
                const float so = fsig(ov);
                const float cn = sf * cold + si * ftanh(gv);
                const float hn = so * ftanh(cn);
                const bool valid = len_lds[b] > u;   // un-reversed mask (reference quirk)
                const float c2 = valid ? cn : cold;
                const float h2 = valid ? hn : hold;
                c_lds[b][jj] = c2;
                h_lds[b][jj] = h2;
                hpair[k2] = h2;
                if (layer == 1) {
                    const int tout = dir ? (NT - 1 - u) : u;
                    __builtin_nontemporal_store(
                        h2, &out[((size_t)b * NT + tout) * (2 * NH) + dir * NH + j0 + jj]);
                    if (u == NT - 1)
                        __builtin_nontemporal_store(
                            h2, &out[(size_t)NB * NT * (2 * NH) + (size_t)b * (2 * NH)
                                     + dir * NH + j0 + jj]);
                }
            }
            // h handoff into fresh ring slot u+1 (single fp16 plane, sc1 store)
            half_t* hb2 = hring + ((size_t)(u + 1) * 4 + c) * HPLANE
                        + (size_t)b * NH + j0 + jj0;
            store_h2(hb2, (half_t)hpair[0], (half_t)hpair[1]);
        }

        // ---- flat per-combo barrier: one atomic, poll the counter directly ----
        const int target = (s + 1) * 64;
        __syncthreads();                    // vmcnt(0): sc1 h-stores visible
        if (tid == 0) {
            __hip_atomic_fetch_add(cnt_own, 1, __ATOMIC_RELAXED,
                                   __HIP_MEMORY_SCOPE_AGENT);
            while (__hip_atomic_load(cnt_own, __ATOMIC_RELAXED,
                                     __HIP_MEMORY_SCOPE_AGENT) < target)
                __builtin_amdgcn_s_sleep(1);
            if (layer == 1) {               // same-dir L0 runs ahead; normally ready
                while (__hip_atomic_load(cnt_dep, __ATOMIC_RELAXED,
                                         __HIP_MEMORY_SCOPE_AGENT) < target)
                    __builtin_amdgcn_s_sleep(1);
            }
        }
        __syncthreads();
    }
}

extern "C" void kernel_launch(void* const* d_in, const int* in_sizes, int n_in,
                              void* d_out, int out_size, void* d_ws, size_t ws_size,
                              hipStream_t stream) {
    (void)in_sizes; (void)n_in; (void)out_size; (void)ws_size;
    const float* x     = (const float*)d_in[0];
    const int*   len   = (const int*)d_in[1];
    const float* fw_Wx = (const float*)d_in[2];
    const float* fw_Wh = (const float*)d_in[3];
    const float* fw_b  = (const float*)d_in[4];
    const float* bw_Wx = (const float*)d_in[5];
    const float* bw_Wh = (const float*)d_in[6];
    const float* bw_b  = (const float*)d_in[7];
    float* out = (float*)d_out;

    char* ws = (char*)d_ws;
    size_t off = 0;
    half_t* WT = (half_t*)(ws + off); off += (size_t)2048 * WREG * 2;   // 64 MB
    half_t* xh = (half_t*)(ws + off); off += XPLANE * 2;                // 32 MB
    int* bar = (int*)(ws + off); off += 4096;                           // 4 KB
    half_t* hring = (half_t*)(ws + off);                                // 134.7 MB

    // zero barrier counters + ring slot 0 (4 combos x 128 KB = 512 KB)
    hipMemsetAsync(bar, 0, 4096 + (size_t)4 * HPLANE * 2, stream);

    cvt_x<<<NB * NT, 256, 0, stream>>>(x, xh);

    dim3 tg(G4 / 64, ND / 64, 8);
    transpose_pack<<<tg, 256, 0, stream>>>(fw_Wx, fw_Wh, bw_Wx, bw_Wh, WT);

    void* args[] = {(void*)&xh, (void*)&len, (void*)&fw_b, (void*)&bw_b,
                    (void*)&WT, (void*)&hring, (void*)&out, (void*)&bar};
    hipLaunchCooperativeKernel((void*)lstm_persistent, dim3(256), dim3(512),
                               args, 0, stream);
}